// Round 2
// baseline (689.401 us; speedup 1.0000x reference)
//
#include <hip/hip_runtime.h>
#include <math.h>

// Problem constants
#define SB 4
#define SS 2048
#define SD 1024
#define SH 16
#define SHD 64
#define SM (SB * SS) // 8192 rows

using f32x4 = __attribute__((ext_vector_type(4))) float;
using s16x8 = __attribute__((ext_vector_type(8))) short;
using h8    = __attribute__((ext_vector_type(8))) _Float16;

__device__ __forceinline__ unsigned short f2bf(float x) {
  unsigned int u = __float_as_uint(x);
  u = (u + 0x7fffu + ((u >> 16) & 1u)) >> 16; // RNE
  return (unsigned short)u;
}
__device__ __forceinline__ unsigned short f2h(float x) {
  _Float16 h = (_Float16)x;
  return __builtin_bit_cast(unsigned short, h);
}
// pack two positive floats to bf16x2, round-half-up (1/2-ulp bias, fine for p>0)
__device__ __forceinline__ unsigned int bfpack(float a, float b) {
  unsigned int ua = __float_as_uint(a) + 0x8000u;
  unsigned int ub = __float_as_uint(b) + 0x8000u;
  return (ua >> 16) | (ub & 0xffff0000u);
}

__device__ __forceinline__ void gld_lds16(const unsigned short* g, unsigned short* l) {
  __builtin_amdgcn_global_load_lds(
      (const __attribute__((address_space(1))) unsigned int*)g,
      (__attribute__((address_space(3))) unsigned int*)l, 16, 0, 0);
}

// ---------------- fp32 -> fp16 convert (4 elems/thread) ----------------
__global__ __launch_bounds__(256) void cvt4h(const float* __restrict__ in,
                                             unsigned short* __restrict__ out, int n4) {
  int i = blockIdx.x * 256 + threadIdx.x;
  if (i >= n4) return;
  float4 v = ((const float4*)in)[i];
  unsigned long long r = (unsigned long long)f2h(v.x)
                       | ((unsigned long long)f2h(v.y) << 16)
                       | ((unsigned long long)f2h(v.z) << 32)
                       | ((unsigned long long)f2h(v.w) << 48);
  ((unsigned long long*)out)[i] = r;
}

// ---------------- fused QKV projection GEMM (fp16 in, Q/K fp16 out, V bf16 out) --
__global__ __launch_bounds__(256) void gemm_qkv(
    const unsigned short* __restrict__ Xh,
    const unsigned short* __restrict__ Wqh, const unsigned short* __restrict__ Wkh,
    const unsigned short* __restrict__ Wvh,
    const float* __restrict__ bq, const float* __restrict__ bk, const float* __restrict__ bv,
    unsigned short* __restrict__ Qh, unsigned short* __restrict__ Kh,
    unsigned short* __restrict__ Vb) {
  __shared__ unsigned short lA[128 * 32];
  __shared__ unsigned short lB[128 * 32];
  const int z = blockIdx.z;
  const unsigned short* W = (z == 0) ? Wqh : (z == 1) ? Wkh : Wvh;
  const float* bias = (z == 0) ? bq : (z == 1) ? bk : bv;
  unsigned short* C = (z == 0) ? Qh : (z == 1) ? Kh : Vb;

  const int tid = threadIdx.x;
  const int wave = tid >> 6, lane = tid & 63;
  const int quad = lane >> 4, l16 = lane & 15;
  const int tN = blockIdx.x * 128, tM = blockIdx.y * 128;
  const int wr = (wave >> 1) * 64, wc = (wave & 1) * 64;

  f32x4 acc[4][4] = {};

  const int c0 = tid, c1 = 256 + tid;
  const int r0 = c0 >> 2, q0 = (c0 & 3) * 8;
  const int r1 = c1 >> 2, q1 = (c1 & 3) * 8;
  const unsigned short* gA0 = Xh + (size_t)(tM + r0) * SD + q0;
  const unsigned short* gB0 = W  + (size_t)(tN + r0) * SD + q0;
  const unsigned short* gA1 = Xh + (size_t)(tM + r1) * SD + q1;
  const unsigned short* gB1 = W  + (size_t)(tN + r1) * SD + q1;
  unsigned short* lA0 = lA + (wave * 64) * 8;
  unsigned short* lB0 = lB + (wave * 64) * 8;
  unsigned short* lA1 = lA + (256 + wave * 64) * 8;
  unsigned short* lB1 = lB + (256 + wave * 64) * 8;

  for (int k0 = 0; k0 < SD; k0 += 32) {
    __syncthreads();
    gld_lds16(gA0 + k0, lA0);
    gld_lds16(gB0 + k0, lB0);
    gld_lds16(gA1 + k0, lA1);
    gld_lds16(gB1 + k0, lB1);
    __syncthreads();

    h8 af[4], bf[4];
#pragma unroll
    for (int i = 0; i < 4; ++i)
      af[i] = *(const h8*)(lA + (wr + i * 16 + l16) * 32 + quad * 8);
#pragma unroll
    for (int i = 0; i < 4; ++i)
      bf[i] = *(const h8*)(lB + (wc + i * 16 + l16) * 32 + quad * 8);
#pragma unroll
    for (int mi = 0; mi < 4; ++mi)
#pragma unroll
      for (int ni = 0; ni < 4; ++ni)
        acc[mi][ni] = __builtin_amdgcn_mfma_f32_16x16x32_f16(af[mi], bf[ni], acc[mi][ni], 0, 0, 0);
  }

  // epilogue: C/D layout col=lane&15, row=quad*4+reg
  if (z == 2) {
#pragma unroll
    for (int ni = 0; ni < 4; ++ni) {
      const int gn = tN + wc + ni * 16 + l16;
      const float bb = bias[gn];
#pragma unroll
      for (int mi = 0; mi < 4; ++mi)
#pragma unroll
        for (int r = 0; r < 4; ++r) {
          const int gm = tM + wr + mi * 16 + quad * 4 + r;
          C[(size_t)gm * SD + gn] = f2bf(acc[mi][ni][r] + bb);
        }
    }
  } else {
#pragma unroll
    for (int ni = 0; ni < 4; ++ni) {
      const int gn = tN + wc + ni * 16 + l16;
      const float bb = bias[gn];
#pragma unroll
      for (int mi = 0; mi < 4; ++mi)
#pragma unroll
        for (int r = 0; r < 4; ++r) {
          const int gm = tM + wr + mi * 16 + quad * 4 + r;
          C[(size_t)gm * SD + gn] = f2h(acc[mi][ni][r] + bb);
        }
    }
  }
}

// ---------------- V transpose: [B,S,D] -> Vt[(bh*64 + d)][S]  (bf16, dtype-agnostic)
__global__ __launch_bounds__(256) void transpose_v(const unsigned short* __restrict__ Vb,
                                                   unsigned short* __restrict__ Vt) {
  __shared__ unsigned short tv[64][70];
  const int tid = threadIdx.x;
  const int st = blockIdx.x * 64;
  const int bh = blockIdx.y;
  const int b = bh >> 4, h = bh & 15;
#pragma unroll
  for (int i = 0; i < 2; ++i) {
    int idx = i * 256 + tid;
    int sl = idx >> 3, c8 = idx & 7;
    const unsigned short* src = Vb + ((size_t)(b * SS + st + sl)) * SD + h * 64 + c8 * 8;
    uint4 v = *(const uint4*)src;
    unsigned int* d32 = (unsigned int*)&tv[sl][c8 * 8];
    d32[0] = v.x; d32[1] = v.y; d32[2] = v.z; d32[3] = v.w;
  }
  __syncthreads();
#pragma unroll
  for (int i = 0; i < 2; ++i) {
    int idx = i * 256 + tid;
    int dl = idx >> 3, sc = idx & 7;
    unsigned short tmp[8];
#pragma unroll
    for (int j = 0; j < 8; ++j) tmp[j] = tv[sc * 8 + j][dl];
    uint4 v;
    v.x = tmp[0] | ((unsigned)tmp[1] << 16);
    v.y = tmp[2] | ((unsigned)tmp[3] << 16);
    v.z = tmp[4] | ((unsigned)tmp[5] << 16);
    v.w = tmp[6] | ((unsigned)tmp[7] << 16);
    *(uint4*)(Vt + ((size_t)(bh * 64 + dl)) * SS + st + sc * 8) = v;
  }
}

// ---------------- attention, no-max softmax, S^T layout ----------------
// S^T = K·Q^T : mfma(A=Kfrag, B=Qfrag) -> D[m=key][n=query]
//   C-layout: col=l16=query, row=quad*4+r=key  -> lane holds 1 query, 16 keys
// P pack: 4 consecutive keys/lane/nt -> ds_write_b64 into pl[query][key] (stride 76)
// PV:  O^T[d][q] = mfma(A=Vt-frag, B=P-frag)
__global__ __launch_bounds__(256, 4) void attn(const unsigned short* __restrict__ Qh,
                                               const unsigned short* __restrict__ Kh,
                                               const unsigned short* __restrict__ Vt,
                                               float* __restrict__ out) {
  __shared__ unsigned short pl[4 * 16 * 76]; // per-wave P tile [16 q][64 k], stride 76
  const int tid = threadIdx.x;
  const int wave = tid >> 6, lane = tid & 63;
  const int quad = lane >> 4, l16 = lane & 15;
  // XCD swizzle: all 32 q-tiles of one bh land on the same XCD (bid%8 == bh%8)
  const int bid = blockIdx.x;
  const int bh = (bid & 7) | (((bid >> 3) & 7) << 3);
  const int qt = bid >> 6;
  const int b = bh >> 4, h = bh & 15;
  const int qs = qt * 64 + wave * 16;

  // Q as B-operand, pre-scaled by 1/8*log2(e)
  const _Float16 c2 = (_Float16)0.18033688011112042f;
  const unsigned short* qp = Qh + ((size_t)(b * SS + qs + l16)) * SD + h * 64 + quad * 8;
  h8 aq0 = *(const h8*)(qp) * c2;
  h8 aq1 = *(const h8*)(qp + 32) * c2;

  const unsigned short* kbp = Kh + ((size_t)(b * SS)) * SD + h * 64; // + key*SD + d
  const unsigned short* vbp = Vt + ((size_t)(bh * 64)) * SS;        // + d*SS + key

  f32x4 ov[4] = {};
  float l_acc = 0.f;
  unsigned short* pw = pl + wave * 16 * 76;
  unsigned short* pwr = pw + l16 * 76; // this lane's P row (query = l16)

  for (int kt = 0; kt < 32; ++kt) {
    const int k0 = kt * 64;
    f32x4 s[4] = {};
    const unsigned short* kp = kbp + (size_t)(k0 + l16) * SD + quad * 8;
#pragma unroll
    for (int nt = 0; nt < 4; ++nt) {
      const unsigned short* kr = kp + (size_t)nt * 16 * SD;
      h8 kf0 = *(const h8*)(kr);
      h8 kf1 = *(const h8*)(kr + 32);
      s[nt] = __builtin_amdgcn_mfma_f32_16x16x32_f16(kf0, aq0, s[nt], 0, 0, 0);
      s[nt] = __builtin_amdgcn_mfma_f32_16x16x32_f16(kf1, aq1, s[nt], 0, 0, 0);
    }
    // p = exp2(s) (scale folded into Q); accumulate l per-lane; pack to bf16
#pragma unroll
    for (int nt = 0; nt < 4; ++nt) {
      float p0 = __builtin_amdgcn_exp2f(s[nt][0]);
      float p1 = __builtin_amdgcn_exp2f(s[nt][1]);
      float p2 = __builtin_amdgcn_exp2f(s[nt][2]);
      float p3 = __builtin_amdgcn_exp2f(s[nt][3]);
      l_acc += (p0 + p1) + (p2 + p3);
      uint2 w;
      w.x = bfpack(p0, p1);
      w.y = bfpack(p2, p3);
      *(uint2*)(pwr + nt * 16 + quad * 4) = w; // keys nt*16+quad*4..+3
    }
    asm volatile("s_waitcnt lgkmcnt(0)" ::: "memory");
    s16x8 pa0 = *(const s16x8*)(pwr + quad * 8);      // keys 0..31 of tile
    s16x8 pa1 = *(const s16x8*)(pwr + 32 + quad * 8); // keys 32..63
    const unsigned short* vp = vbp + (size_t)l16 * SS + k0 + quad * 8;
#pragma unroll
    for (int f = 0; f < 4; ++f) {
      const unsigned short* vr = vp + (size_t)(f * 16) * SS;
      s16x8 v0 = *(const s16x8*)(vr);
      s16x8 v1 = *(const s16x8*)(vr + 32);
      ov[f] = __builtin_amdgcn_mfma_f32_16x16x32_bf16(v0, pa0, ov[f], 0, 0, 0);
      ov[f] = __builtin_amdgcn_mfma_f32_16x16x32_bf16(v1, pa1, ov[f], 0, 0, 0);
    }
  }
  // l: reduce partial sums across quads (same query = l16)
  float lt = l_acc;
  lt += __shfl_xor(lt, 16);
  lt += __shfl_xor(lt, 32);
  const float inv = 1.0f / lt;
  // O^T: lane(quad,l16) holds query=l16, d = f*16 + quad*4 + r -> 4x float4 stores
  float* orow = out + ((size_t)(b * SS + qs + l16)) * SD + h * 64 + quad * 4;
#pragma unroll
  for (int f = 0; f < 4; ++f) {
    float4 w;
    w.x = ov[f][0] * inv; w.y = ov[f][1] * inv;
    w.z = ov[f][2] * inv; w.w = ov[f][3] * inv;
    *(float4*)(orow + f * 16) = w;
  }
}

extern "C" void kernel_launch(void* const* d_in, const int* in_sizes, int n_in,
                              void* d_out, int out_size, void* d_ws, size_t ws_size,
                              hipStream_t stream) {
  const float* hs = (const float*)d_in[0];
  const float* Wq = (const float*)d_in[1];
  const float* bq = (const float*)d_in[2];
  const float* Wk = (const float*)d_in[3];
  const float* bk = (const float*)d_in[4];
  const float* Wv = (const float*)d_in[5];
  const float* bv = (const float*)d_in[6];
  float* out = (float*)d_out;

  char* ws = (char*)d_ws;
  // layout: Xh 16M | Wq/Wk/Wv 2M each | Qh/Kh/Vb/Vt 16M each ~ 86MB
  unsigned short* Xh  = (unsigned short*)(ws);
  unsigned short* Wqh = (unsigned short*)(ws + 16777216);
  unsigned short* Wkh = (unsigned short*)(ws + 16777216 + 2097152);
  unsigned short* Wvh = (unsigned short*)(ws + 16777216 + 2 * 2097152);
  unsigned short* Qh  = (unsigned short*)(ws + 16777216 + 3 * 2097152);
  unsigned short* Kh  = Qh + (size_t)SM * SD;
  unsigned short* Vb  = Kh + (size_t)SM * SD;
  unsigned short* Vt  = Vb + (size_t)SM * SD;

  cvt4h<<<dim3(8192), dim3(256), 0, stream>>>(hs, Xh, SM * SD / 4);
  cvt4h<<<dim3(1024), dim3(256), 0, stream>>>(Wq, Wqh, SD * SD / 4);
  cvt4h<<<dim3(1024), dim3(256), 0, stream>>>(Wk, Wkh, SD * SD / 4);
  cvt4h<<<dim3(1024), dim3(256), 0, stream>>>(Wv, Wvh, SD * SD / 4);
  gemm_qkv<<<dim3(SD / 128, SM / 128, 3), dim3(256), 0, stream>>>(
      Xh, Wqh, Wkh, Wvh, bq, bk, bv, Qh, Kh, Vb);
  transpose_v<<<dim3(SS / 64, SB * SH), dim3(256), 0, stream>>>(Vb, Vt);
  attn<<<dim3(SB * SH * (SS / 64)), dim3(256), 0, stream>>>(Qh, Kh, Vt, out);
}

// Round 3
// 312.038 us; speedup vs baseline: 2.2093x; 2.2093x over previous
//
#include <hip/hip_runtime.h>
#include <math.h>

// Problem constants
#define SB 4
#define SS 2048
#define SD 1024
#define SH 16
#define SHD 64
#define SM (SB * SS) // 8192 rows

using f32x4 = __attribute__((ext_vector_type(4))) float;
using s16x8 = __attribute__((ext_vector_type(8))) short;
using h8    = __attribute__((ext_vector_type(8))) _Float16;

__device__ __forceinline__ unsigned short f2bf(float x) {
  unsigned int u = __float_as_uint(x);
  u = (u + 0x7fffu + ((u >> 16) & 1u)) >> 16; // RNE
  return (unsigned short)u;
}
__device__ __forceinline__ unsigned short f2h(float x) {
  _Float16 h = (_Float16)x;
  return __builtin_bit_cast(unsigned short, h);
}
// pack two positive floats to bf16x2, round-half-up
__device__ __forceinline__ unsigned int bfpack(float a, float b) {
  unsigned int ua = __float_as_uint(a) + 0x8000u;
  unsigned int ub = __float_as_uint(b) + 0x8000u;
  return (ua >> 16) | (ub & 0xffff0000u);
}

__device__ __forceinline__ void gld_lds16(const unsigned short* g, unsigned short* l) {
  __builtin_amdgcn_global_load_lds(
      (const __attribute__((address_space(1))) unsigned int*)g,
      (__attribute__((address_space(3))) unsigned int*)l, 16, 0, 0);
}

// ---------------- fp32 -> fp16 convert (4 elems/thread) ----------------
__global__ __launch_bounds__(256) void cvt4h(const float* __restrict__ in,
                                             unsigned short* __restrict__ out, int n4) {
  int i = blockIdx.x * 256 + threadIdx.x;
  if (i >= n4) return;
  float4 v = ((const float4*)in)[i];
  unsigned long long r = (unsigned long long)f2h(v.x)
                       | ((unsigned long long)f2h(v.y) << 16)
                       | ((unsigned long long)f2h(v.z) << 32)
                       | ((unsigned long long)f2h(v.w) << 48);
  ((unsigned long long*)out)[i] = r;
}

// ---------------- fused QKV projection GEMM ----------------
// z==0: Qh = (X@Wq^T + bq) * (1/8*log2e)  fp16, [s][1024]
// z==1: Kh =  X@Wk^T + bk                 fp16, [s][1024]
// z==2: Vt =  X@Wv^T + bv                 bf16, transposed [bh*64+d][s]
__global__ __launch_bounds__(256) void gemm_qkv(
    const unsigned short* __restrict__ Xh,
    const unsigned short* __restrict__ Wqh, const unsigned short* __restrict__ Wkh,
    const unsigned short* __restrict__ Wvh,
    const float* __restrict__ bq, const float* __restrict__ bk, const float* __restrict__ bv,
    unsigned short* __restrict__ Qh, unsigned short* __restrict__ Kh,
    unsigned short* __restrict__ Vt) {
  __shared__ unsigned short lA[128 * 32];
  __shared__ unsigned short lB[128 * 32];
  const int z = blockIdx.z;
  const unsigned short* W = (z == 0) ? Wqh : (z == 1) ? Wkh : Wvh;
  const float* bias = (z == 0) ? bq : (z == 1) ? bk : bv;

  const int tid = threadIdx.x;
  const int wave = tid >> 6, lane = tid & 63;
  const int quad = lane >> 4, l16 = lane & 15;
  const int tN = blockIdx.x * 128, tM = blockIdx.y * 128;
  const int wr = (wave >> 1) * 64, wc = (wave & 1) * 64;

  f32x4 acc[4][4] = {};

  const int c0 = tid, c1 = 256 + tid;
  const int r0 = c0 >> 2, q0 = (c0 & 3) * 8;
  const int r1 = c1 >> 2, q1 = (c1 & 3) * 8;
  const unsigned short* gA0 = Xh + (size_t)(tM + r0) * SD + q0;
  const unsigned short* gB0 = W  + (size_t)(tN + r0) * SD + q0;
  const unsigned short* gA1 = Xh + (size_t)(tM + r1) * SD + q1;
  const unsigned short* gB1 = W  + (size_t)(tN + r1) * SD + q1;
  unsigned short* lA0 = lA + (wave * 64) * 8;
  unsigned short* lB0 = lB + (wave * 64) * 8;
  unsigned short* lA1 = lA + (256 + wave * 64) * 8;
  unsigned short* lB1 = lB + (256 + wave * 64) * 8;

  for (int k0 = 0; k0 < SD; k0 += 32) {
    __syncthreads();
    gld_lds16(gA0 + k0, lA0);
    gld_lds16(gB0 + k0, lB0);
    gld_lds16(gA1 + k0, lA1);
    gld_lds16(gB1 + k0, lB1);
    __syncthreads();

    h8 af[4], bf[4];
#pragma unroll
    for (int i = 0; i < 4; ++i)
      af[i] = *(const h8*)(lA + (wr + i * 16 + l16) * 32 + quad * 8);
#pragma unroll
    for (int i = 0; i < 4; ++i)
      bf[i] = *(const h8*)(lB + (wc + i * 16 + l16) * 32 + quad * 8);
#pragma unroll
    for (int mi = 0; mi < 4; ++mi)
#pragma unroll
      for (int ni = 0; ni < 4; ++ni)
        acc[mi][ni] = __builtin_amdgcn_mfma_f32_16x16x32_f16(af[mi], bf[ni], acc[mi][ni], 0, 0, 0);
  }

  // epilogue: C/D layout col=lane&15, row=quad*4+reg
  if (z == 2) {
    // Vt[(b*16 + gn/64)*64 + gn%64][s] = bf16(acc+b) ; consecutive r contiguous
#pragma unroll
    for (int ni = 0; ni < 4; ++ni) {
      const int gn = tN + wc + ni * 16 + l16;
      const float bb = bias[gn];
#pragma unroll
      for (int mi = 0; mi < 4; ++mi) {
        const int gm = tM + wr + mi * 16 + quad * 4;
        const int vb = gm >> 11, vs = gm & 2047;
        unsigned long long wv = 0;
#pragma unroll
        for (int r = 0; r < 4; ++r)
          wv |= (unsigned long long)f2bf(acc[mi][ni][r] + bb) << (16 * r);
        *(unsigned long long*)(Vt + (size_t)(vb * 1024 + gn) * SS + vs) = wv;
      }
    }
  } else {
    const float sc = (z == 0) ? 0.18033688011112042f : 1.0f; // 1/8*log2(e)
    unsigned short* C = (z == 0) ? Qh : Kh;
#pragma unroll
    for (int ni = 0; ni < 4; ++ni) {
      const int gn = tN + wc + ni * 16 + l16;
      const float bb = bias[gn];
#pragma unroll
      for (int mi = 0; mi < 4; ++mi)
#pragma unroll
        for (int r = 0; r < 4; ++r) {
          const int gm = tM + wr + mi * 16 + quad * 4 + r;
          C[(size_t)gm * SD + gn] = f2h((acc[mi][ni][r] + bb) * sc);
        }
    }
  }
}

// ---------------- attention: block = 64 queries, dbuf LDS K/V tiles ----------------
// S^T = K·Q^T (A=K-frag, B=Q-frag) -> C: col=l16=query, row=quad*4+r=key
// PV:  O^T    (A=Vt-frag, B=P-frag)
// K/V tiles staged via global_load_lds with XOR-swizzled 16B-chunk placement:
//   chunk (row, c) stored at slot row*8 + (c ^ (row&7))  -> frag reads 8 dw/bank
__global__ __launch_bounds__(256, 3) void attn(const unsigned short* __restrict__ Qh,
                                               const unsigned short* __restrict__ Kh,
                                               const unsigned short* __restrict__ Vt,
                                               float* __restrict__ out) {
  __shared__ unsigned short lK[2][64 * 64]; // [buf][key-tile]  8KB each
  __shared__ unsigned short lV[2][64 * 64]; // [buf][d-tile]    8KB each
  __shared__ unsigned short pl[4 * 16 * 80]; // per-wave P [16 q][64 k], stride 80
  const int tid = threadIdx.x;
  const int wave = tid >> 6, lane = tid & 63;
  const int quad = lane >> 4, l16 = lane & 15;
  // XCD swizzle: all 32 q-tiles of one bh share an XCD (bid%8 == bh%8)
  const int bid = blockIdx.x;
  const int bh = (bid & 7) | (((bid >> 3) & 7) << 3);
  const int qt = bid >> 6;
  const int b = bh >> 4, h = bh & 15;
  const int qs = qt * 64 + wave * 16;

  // Q fragments (scale pre-folded in GEMM epilogue)
  const unsigned short* qp = Qh + ((size_t)(b * SS + qs + l16)) * SD + h * 64 + quad * 8;
  h8 aq0 = *(const h8*)(qp);
  h8 aq1 = *(const h8*)(qp + 32);

  // staging source pointers: thread handles tile chunks tid and 256+tid
  const int row0 = tid >> 3, cs0 = (tid & 7) ^ (row0 & 7);
  const int row1 = row0 + 32, cs1 = (tid & 7) ^ (row1 & 7);
  const unsigned short* kS0 = Kh + ((size_t)(b * SS + row0)) * SD + h * 64 + cs0 * 8;
  const unsigned short* kS1 = Kh + ((size_t)(b * SS + row1)) * SD + h * 64 + cs1 * 8;
  const unsigned short* vS0 = Vt + ((size_t)(bh * 64 + row0)) * SS + cs0 * 8;
  const unsigned short* vS1 = Vt + ((size_t)(bh * 64 + row1)) * SS + cs1 * 8;
  unsigned short* dK0 = &lK[0][wave * 512];        // wave-uniform LDS dests
  unsigned short* dK1 = &lK[0][2048 + wave * 512];
  unsigned short* dV0 = &lV[0][wave * 512];
  unsigned short* dV1 = &lV[0][2048 + wave * 512];

  f32x4 ov[4] = {};
  float l_acc = 0.f;
  unsigned short* pwr = pl + wave * 16 * 80 + l16 * 80;
  const int sw = (l16 & 7) * 8; // chunk-XOR swizzle, in shorts

  // prologue: stage tile 0 into buf 0
  gld_lds16(kS0, dK0); gld_lds16(kS1, dK1);
  gld_lds16(vS0, dV0); gld_lds16(vS1, dV1);
  kS0 += 64 * SD; kS1 += 64 * SD; vS0 += 64; vS1 += 64;

  for (int kt = 0; kt < 32; ++kt) {
    const int buf = kt & 1;
    __syncthreads(); // drains vmcnt: tile kt resident; prev compute on buf^1 done
    if (kt < 31) {
      const int o = (buf ^ 1) * 64 * 64;
      gld_lds16(kS0, dK0 + o); gld_lds16(kS1, dK1 + o);
      gld_lds16(vS0, dV0 + o); gld_lds16(vS1, dV1 + o);
      kS0 += 64 * SD; kS1 += 64 * SD; vS0 += 64; vS1 += 64;
    }
    const unsigned short* Kt = lK[buf];
    const unsigned short* Vl = lV[buf];

    f32x4 s[4] = {};
#pragma unroll
    for (int nt = 0; nt < 4; ++nt) {
      const unsigned short* kr = Kt + (nt * 16 + l16) * 64;
      h8 kf0 = *(const h8*)(kr + (quad * 8 ^ sw));
      h8 kf1 = *(const h8*)(kr + ((32 + quad * 8) ^ sw));
      s[nt] = __builtin_amdgcn_mfma_f32_16x16x32_f16(kf0, aq0, s[nt], 0, 0, 0);
      s[nt] = __builtin_amdgcn_mfma_f32_16x16x32_f16(kf1, aq1, s[nt], 0, 0, 0);
    }
    // p = exp2(s); accumulate l per-lane; pack bf16 into per-wave P tile
#pragma unroll
    for (int nt = 0; nt < 4; ++nt) {
      float p0 = __builtin_amdgcn_exp2f(s[nt][0]);
      float p1 = __builtin_amdgcn_exp2f(s[nt][1]);
      float p2 = __builtin_amdgcn_exp2f(s[nt][2]);
      float p3 = __builtin_amdgcn_exp2f(s[nt][3]);
      l_acc += (p0 + p1) + (p2 + p3);
      uint2 w;
      w.x = bfpack(p0, p1);
      w.y = bfpack(p2, p3);
      *(uint2*)(pwr + nt * 16 + quad * 4) = w;
    }
    asm volatile("s_waitcnt lgkmcnt(0)" ::: "memory");
    s16x8 pa0 = *(const s16x8*)(pwr + quad * 8);
    s16x8 pa1 = *(const s16x8*)(pwr + 32 + quad * 8);
#pragma unroll
    for (int f = 0; f < 4; ++f) {
      const unsigned short* vr = Vl + (f * 16 + l16) * 64;
      s16x8 v0 = *(const s16x8*)(vr + (quad * 8 ^ sw));
      s16x8 v1 = *(const s16x8*)(vr + ((32 + quad * 8) ^ sw));
      ov[f] = __builtin_amdgcn_mfma_f32_16x16x32_bf16(v0, pa0, ov[f], 0, 0, 0);
      ov[f] = __builtin_amdgcn_mfma_f32_16x16x32_bf16(v1, pa1, ov[f], 0, 0, 0);
    }
  }
  // l: reduce across quads (same query = l16)
  float lt = l_acc;
  lt += __shfl_xor(lt, 16);
  lt += __shfl_xor(lt, 32);
  const float inv = 1.0f / lt;
  // O^T: lane holds query=l16, d = f*16 + quad*4 + r -> 4x float4 stores
  float* orow = out + ((size_t)(b * SS + qs + l16)) * SD + h * 64 + quad * 4;
#pragma unroll
  for (int f = 0; f < 4; ++f) {
    float4 w;
    w.x = ov[f][0] * inv; w.y = ov[f][1] * inv;
    w.z = ov[f][2] * inv; w.w = ov[f][3] * inv;
    *(float4*)(orow + f * 16) = w;
  }
}

extern "C" void kernel_launch(void* const* d_in, const int* in_sizes, int n_in,
                              void* d_out, int out_size, void* d_ws, size_t ws_size,
                              hipStream_t stream) {
  const float* hs = (const float*)d_in[0];
  const float* Wq = (const float*)d_in[1];
  const float* bq = (const float*)d_in[2];
  const float* Wk = (const float*)d_in[3];
  const float* bk = (const float*)d_in[4];
  const float* Wv = (const float*)d_in[5];
  const float* bv = (const float*)d_in[6];
  float* out = (float*)d_out;

  char* ws = (char*)d_ws;
  // layout: Xh 16M | Wq/Wk/Wv 2M each | Qh/Kh/Vt 16M each ~ 70MB
  unsigned short* Xh  = (unsigned short*)(ws);
  unsigned short* Wqh = (unsigned short*)(ws + 16777216);
  unsigned short* Wkh = (unsigned short*)(ws + 16777216 + 2097152);
  unsigned short* Wvh = (unsigned short*)(ws + 16777216 + 2 * 2097152);
  unsigned short* Qh  = (unsigned short*)(ws + 16777216 + 3 * 2097152);
  unsigned short* Kh  = Qh + (size_t)SM * SD;
  unsigned short* Vt  = Kh + (size_t)SM * SD;

  cvt4h<<<dim3(8192), dim3(256), 0, stream>>>(hs, Xh, SM * SD / 4);
  cvt4h<<<dim3(1024), dim3(256), 0, stream>>>(Wq, Wqh, SD * SD / 4);
  cvt4h<<<dim3(1024), dim3(256), 0, stream>>>(Wk, Wkh, SD * SD / 4);
  cvt4h<<<dim3(1024), dim3(256), 0, stream>>>(Wv, Wvh, SD * SD / 4);
  gemm_qkv<<<dim3(SD / 128, SM / 128, 3), dim3(256), 0, stream>>>(
      Xh, Wqh, Wkh, Wvh, bq, bk, bv, Qh, Kh, Vt);
  attn<<<dim3(SB * SH * (SS / 64)), dim3(256), 0, stream>>>(Qh, Kh, Vt, out);
}

// Round 5
// 273.721 us; speedup vs baseline: 2.5186x; 1.1400x over previous
//
#include <hip/hip_runtime.h>
#include <math.h>

// Problem constants
#define SB 4
#define SS 2048
#define SD 1024
#define SH 16
#define SHD 64
#define SM (SB * SS) // 8192 rows

using f32x4 = __attribute__((ext_vector_type(4))) float;
using h8    = __attribute__((ext_vector_type(8))) _Float16;
using h4    = __attribute__((ext_vector_type(4))) _Float16;
using fp16x2 = __fp16 __attribute__((ext_vector_type(2)));
using fp16x4 = __fp16 __attribute__((ext_vector_type(4)));

__device__ __forceinline__ unsigned short f2h(float x) {
  _Float16 h = (_Float16)x;
  return __builtin_bit_cast(unsigned short, h);
}

__device__ __forceinline__ void gld_lds16(const unsigned short* g, unsigned short* l) {
  __builtin_amdgcn_global_load_lds(
      (const __attribute__((address_space(1))) unsigned int*)g,
      (__attribute__((address_space(3))) unsigned int*)l, 16, 0, 0);
}

// ---------------- fp32 -> fp16 convert (4 elems/thread) ----------------
__global__ __launch_bounds__(256) void cvt4h(const float* __restrict__ in,
                                             unsigned short* __restrict__ out, int n4) {
  int i = blockIdx.x * 256 + threadIdx.x;
  if (i >= n4) return;
  float4 v = ((const float4*)in)[i];
  unsigned long long r = (unsigned long long)f2h(v.x)
                       | ((unsigned long long)f2h(v.y) << 16)
                       | ((unsigned long long)f2h(v.z) << 32)
                       | ((unsigned long long)f2h(v.w) << 48);
  ((unsigned long long*)out)[i] = r;
}

// three weight converts in one dispatch (saves 2 launch overheads)
__global__ __launch_bounds__(256) void cvt3w(const float* __restrict__ w0, const float* __restrict__ w1,
                                             const float* __restrict__ w2,
                                             unsigned short* __restrict__ o0, unsigned short* __restrict__ o1,
                                             unsigned short* __restrict__ o2) {
  const int z = blockIdx.y;
  const float* in = (z == 0) ? w0 : (z == 1) ? w1 : w2;
  unsigned short* out = (z == 0) ? o0 : (z == 1) ? o1 : o2;
  int i = blockIdx.x * 256 + threadIdx.x; // n4 = 1024*1024/4 = 262144, grid.x=1024
  float4 v = ((const float4*)in)[i];
  unsigned long long r = (unsigned long long)f2h(v.x)
                       | ((unsigned long long)f2h(v.y) << 16)
                       | ((unsigned long long)f2h(v.z) << 32)
                       | ((unsigned long long)f2h(v.w) << 48);
  ((unsigned long long*)out)[i] = r;
}

// ---------------- fused QKV projection GEMM, BK=64 ----------------
// z==0: Qh = (X@Wq^T + bq) * (1/8*log2e)  fp16, [s][1024]
// z==1: Kh =  X@Wk^T + bk                 fp16, [s][1024]
// z==2: Vt =  X@Wv^T + bv                 fp16, transposed [bh*64+d][s]
// LDS tiles [128][64] with XOR-swizzled 16B chunks: chunk c of row r at slot c^(r&7)
__global__ __launch_bounds__(256) void gemm_qkv(
    const unsigned short* __restrict__ Xh,
    const unsigned short* __restrict__ Wqh, const unsigned short* __restrict__ Wkh,
    const unsigned short* __restrict__ Wvh,
    const float* __restrict__ bq, const float* __restrict__ bk, const float* __restrict__ bv,
    unsigned short* __restrict__ Qh, unsigned short* __restrict__ Kh,
    unsigned short* __restrict__ Vt) {
  __shared__ unsigned short lA[128 * 64]; // 16 KB
  __shared__ unsigned short lB[128 * 64]; // 16 KB
  const int z = blockIdx.z;
  const unsigned short* W = (z == 0) ? Wqh : (z == 1) ? Wkh : Wvh;
  const float* bias = (z == 0) ? bq : (z == 1) ? bk : bv;

  const int tid = threadIdx.x;
  const int wave = tid >> 6, lane = tid & 63;
  const int quad = lane >> 4, l16 = lane & 15;
  const int tN = blockIdx.x * 128, tM = blockIdx.y * 128;
  const int wr = (wave >> 1) * 64, wc = (wave & 1) * 64;

  f32x4 acc[4][4] = {};

  // staging: thread handles chunks i*256+tid (i=0..3); row = i*32 + tid>>3
  const int rB = tid >> 3;
  const int colOff = (((tid & 7) ^ (rB & 7))) * 8; // src col = swizzled slot, i-independent
  const unsigned short* gA[4];
  const unsigned short* gB[4];
#pragma unroll
  for (int i = 0; i < 4; ++i) {
    gA[i] = Xh + (size_t)(tM + i * 32 + rB) * SD + colOff;
    gB[i] = W  + (size_t)(tN + i * 32 + rB) * SD + colOff;
  }
  unsigned short* dA[4];
  unsigned short* dB[4];
#pragma unroll
  for (int i = 0; i < 4; ++i) {
    dA[i] = lA + (i * 256 + wave * 64) * 8;
    dB[i] = lB + (i * 256 + wave * 64) * 8;
  }
  const int swl = l16 & 7;

  for (int k0 = 0; k0 < SD; k0 += 64) {
    __syncthreads(); // WAR on previous frag reads
#pragma unroll
    for (int i = 0; i < 4; ++i) gld_lds16(gA[i] + k0, dA[i]);
#pragma unroll
    for (int i = 0; i < 4; ++i) gld_lds16(gB[i] + k0, dB[i]);
    __syncthreads(); // vmcnt drain -> tiles valid

#pragma unroll
    for (int ks = 0; ks < 2; ++ks) {
      h8 af[4], bf[4];
#pragma unroll
      for (int mi = 0; mi < 4; ++mi)
        af[mi] = *(const h8*)(lA + (wr + mi * 16 + l16) * 64 + (((ks * 4 + quad) ^ swl) * 8));
#pragma unroll
      for (int ni = 0; ni < 4; ++ni)
        bf[ni] = *(const h8*)(lB + (wc + ni * 16 + l16) * 64 + (((ks * 4 + quad) ^ swl) * 8));
#pragma unroll
      for (int mi = 0; mi < 4; ++mi)
#pragma unroll
        for (int ni = 0; ni < 4; ++ni)
          acc[mi][ni] = __builtin_amdgcn_mfma_f32_16x16x32_f16(af[mi], bf[ni], acc[mi][ni], 0, 0, 0);
    }
  }

  // epilogue: C/D layout col=lane&15, row=quad*4+reg
  if (z == 2) {
    // Vt[(vb*1024 + gn)][s=vs..vs+3] packed 8B
#pragma unroll
    for (int ni = 0; ni < 4; ++ni) {
      const int gn = tN + wc + ni * 16 + l16;
      const float bb = bias[gn];
#pragma unroll
      for (int mi = 0; mi < 4; ++mi) {
        const int gm = tM + wr + mi * 16 + quad * 4;
        const int vb = gm >> 11, vs = gm & 2047;
        unsigned long long wv = 0;
#pragma unroll
        for (int r = 0; r < 4; ++r)
          wv |= (unsigned long long)f2h(acc[mi][ni][r] + bb) << (16 * r);
        *(unsigned long long*)(Vt + (size_t)(vb * 1024 + gn) * SS + vs) = wv;
      }
    }
  } else {
    const float sc = (z == 0) ? 0.18033688011112042f : 1.0f; // 1/8*log2(e)
    unsigned short* C = (z == 0) ? Qh : Kh;
#pragma unroll
    for (int ni = 0; ni < 4; ++ni) {
      const int gn = tN + wc + ni * 16 + l16;
      const float bb = bias[gn];
#pragma unroll
      for (int mi = 0; mi < 4; ++mi)
#pragma unroll
        for (int r = 0; r < 4; ++r) {
          const int gm = tM + wr + mi * 16 + quad * 4 + r;
          C[(size_t)gm * SD + gn] = f2h((acc[mi][ni][r] + bb) * sc);
        }
    }
  }
}

// ---------------- attention: in-register P via K=16 PV MFMA ----------------
// S^T = K·Q^T (A=K-frag K=32, B=Q-frag) -> C: col=l16=query, row=quad*4+r=key
// p = exp2(s) in-register -> EXACTLY the B-operand layout of mfma_f32_16x16x16f16
//   (B[k=quad*4+j][n=l16]) -> PV needs no LDS round-trip for P.
// PV: O^T[d][q] via A=V^T-frag (ds_read_b64), 4 K=16 groups per 64-key tile.
__global__ __launch_bounds__(256, 4) void attn(const unsigned short* __restrict__ Qh,
                                               const unsigned short* __restrict__ Kh,
                                               const unsigned short* __restrict__ Vt,
                                               float* __restrict__ out) {
  __shared__ unsigned short lK[2][64 * 64]; // 8 KB each
  __shared__ unsigned short lV[2][64 * 64]; // 8 KB each
  const int tid = threadIdx.x;
  const int wave = tid >> 6, lane = tid & 63;
  const int quad = lane >> 4, l16 = lane & 15;
  // XCD swizzle: all 32 q-tiles of one bh share an XCD (bid%8 == bh%8)
  const int bid = blockIdx.x;
  const int bh = (bid & 7) | (((bid >> 3) & 7) << 3);
  const int qt = bid >> 6;
  const int b = bh >> 4, h = bh & 15;
  const int qs = qt * 64 + wave * 16;

  // Q fragments (1/8*log2e pre-folded in GEMM epilogue)
  const unsigned short* qp = Qh + ((size_t)(b * SS + qs + l16)) * SD + h * 64 + quad * 8;
  h8 aq0 = *(const h8*)(qp);
  h8 aq1 = *(const h8*)(qp + 32);

  // staging: thread handles tile chunks tid and 256+tid, XOR-swizzled source
  const int row0 = tid >> 3, cs0 = (tid & 7) ^ (row0 & 7);
  const int row1 = row0 + 32, cs1 = (tid & 7) ^ (row1 & 7);
  const unsigned short* kS0 = Kh + ((size_t)(b * SS + row0)) * SD + h * 64 + cs0 * 8;
  const unsigned short* kS1 = Kh + ((size_t)(b * SS + row1)) * SD + h * 64 + cs1 * 8;
  const unsigned short* vS0 = Vt + ((size_t)(bh * 64 + row0)) * SS + cs0 * 8;
  const unsigned short* vS1 = Vt + ((size_t)(bh * 64 + row1)) * SS + cs1 * 8;
  unsigned short* dK0 = &lK[0][wave * 512];
  unsigned short* dK1 = &lK[0][2048 + wave * 512];
  unsigned short* dV0 = &lV[0][wave * 512];
  unsigned short* dV1 = &lV[0][2048 + wave * 512];

  f32x4 ov[4] = {};
  float l_acc = 0.f;
  const int swl = l16 & 7;

  // prologue: stage tile 0 into buf 0
  gld_lds16(kS0, dK0); gld_lds16(kS1, dK1);
  gld_lds16(vS0, dV0); gld_lds16(vS1, dV1);
  kS0 += 64 * SD; kS1 += 64 * SD; vS0 += 64; vS1 += 64;

  for (int kt = 0; kt < 32; ++kt) {
    const int buf = kt & 1;
    __syncthreads(); // tile kt resident; prev compute on other buf done
    if (kt < 31) {
      const int o = (buf ^ 1) * 64 * 64;
      gld_lds16(kS0, dK0 + o); gld_lds16(kS1, dK1 + o);
      gld_lds16(vS0, dV0 + o); gld_lds16(vS1, dV1 + o);
      kS0 += 64 * SD; kS1 += 64 * SD; vS0 += 64; vS1 += 64;
    }
    const unsigned short* Kt = lK[buf];
    const unsigned short* Vl = lV[buf];

    // QK^T: 8 MFMA K=32
    f32x4 s[4];
#pragma unroll
    for (int nt = 0; nt < 4; ++nt) {
      const unsigned short* kr = Kt + (nt * 16 + l16) * 64;
      h8 kf0 = *(const h8*)(kr + ((quad ^ swl) * 8));
      h8 kf1 = *(const h8*)(kr + (((4 + quad) ^ swl) * 8));
      f32x4 z = {};
      z = __builtin_amdgcn_mfma_f32_16x16x32_f16(kf0, aq0, z, 0, 0, 0);
      s[nt] = __builtin_amdgcn_mfma_f32_16x16x32_f16(kf1, aq1, z, 0, 0, 0);
    }
    // V^T A-fragments for the 4 K=16 groups (b64, swizzled, 2-way free)
    h4 vf[4][4];
#pragma unroll
    for (int nt = 0; nt < 4; ++nt)
#pragma unroll
      for (int f = 0; f < 4; ++f)
        vf[nt][f] = *(const h4*)(Vl + (f * 16 + l16) * 64 +
                                 (((nt * 2 + (quad >> 1)) ^ swl) * 8) + (quad & 1) * 4);
    // p = exp2(s); PV directly from registers
#pragma unroll
    for (int nt = 0; nt < 4; ++nt) {
      float p0 = __builtin_amdgcn_exp2f(s[nt][0]);
      float p1 = __builtin_amdgcn_exp2f(s[nt][1]);
      float p2 = __builtin_amdgcn_exp2f(s[nt][2]);
      float p3 = __builtin_amdgcn_exp2f(s[nt][3]);
      l_acc += (p0 + p1) + (p2 + p3);
      fp16x2 lo = __builtin_amdgcn_cvt_pkrtz(p0, p1);
      fp16x2 hi = __builtin_amdgcn_cvt_pkrtz(p2, p3);
      fp16x4 pp4 = __builtin_shufflevector(lo, hi, 0, 1, 2, 3);
      h4 pp = __builtin_bit_cast(h4, pp4);
#pragma unroll
      for (int f = 0; f < 4; ++f)
        ov[f] = __builtin_amdgcn_mfma_f32_16x16x16f16(vf[nt][f], pp, ov[f], 0, 0, 0);
    }
  }
  // l: reduce across quads (same query = l16); PV p was RTZ of f32 p — ratio bias ~5e-4, ok
  float lt = l_acc;
  lt += __shfl_xor(lt, 16);
  lt += __shfl_xor(lt, 32);
  const float inv = 1.0f / lt;
  // O^T: lane holds query=l16, d = f*16 + quad*4 + r -> 4x float4 stores
  float* orow = out + ((size_t)(b * SS + qs + l16)) * SD + h * 64 + quad * 4;
#pragma unroll
  for (int f = 0; f < 4; ++f) {
    float4 w;
    w.x = ov[f][0] * inv; w.y = ov[f][1] * inv;
    w.z = ov[f][2] * inv; w.w = ov[f][3] * inv;
    *(float4*)(orow + f * 16) = w;
  }
}

extern "C" void kernel_launch(void* const* d_in, const int* in_sizes, int n_in,
                              void* d_out, int out_size, void* d_ws, size_t ws_size,
                              hipStream_t stream) {
  const float* hs = (const float*)d_in[0];
  const float* Wq = (const float*)d_in[1];
  const float* bq = (const float*)d_in[2];
  const float* Wk = (const float*)d_in[3];
  const float* bk = (const float*)d_in[4];
  const float* Wv = (const float*)d_in[5];
  const float* bv = (const float*)d_in[6];
  float* out = (float*)d_out;

  char* ws = (char*)d_ws;
  // layout: Xh 16M | Wq/Wk/Wv 2M each | Qh/Kh/Vt 16M each ~ 70MB
  unsigned short* Xh  = (unsigned short*)(ws);
  unsigned short* Wqh = (unsigned short*)(ws + 16777216);
  unsigned short* Wkh = (unsigned short*)(ws + 16777216 + 2097152);
  unsigned short* Wvh = (unsigned short*)(ws + 16777216 + 2 * 2097152);
  unsigned short* Qh  = (unsigned short*)(ws + 16777216 + 3 * 2097152);
  unsigned short* Kh  = Qh + (size_t)SM * SD;
  unsigned short* Vt  = Kh + (size_t)SM * SD;

  cvt4h<<<dim3(8192), dim3(256), 0, stream>>>(hs, Xh, SM * SD / 4);
  cvt3w<<<dim3(1024, 3), dim3(256), 0, stream>>>(Wq, Wk, Wv, Wqh, Wkh, Wvh);
  gemm_qkv<<<dim3(SD / 128, SM / 128, 3), dim3(256), 0, stream>>>(
      Xh, Wqh, Wkh, Wvh, bq, bk, bv, Qh, Kh, Vt);
  attn<<<dim3(SB * SH * (SS / 64)), dim3(256), 0, stream>>>(Qh, Kh, Vt, out);
}

// Round 6
// 257.526 us; speedup vs baseline: 2.6770x; 1.0629x over previous
//
#include <hip/hip_runtime.h>
#include <math.h>

// Problem constants
#define SB 4
#define SS 2048
#define SD 1024
#define SH 16
#define SHD 64
#define SM (SB * SS) // 8192 rows

using f32x4 = __attribute__((ext_vector_type(4))) float;
using h8    = __attribute__((ext_vector_type(8))) _Float16;
using h4    = __attribute__((ext_vector_type(4))) _Float16;
using fp16x2 = __fp16 __attribute__((ext_vector_type(2)));
using fp16x4 = __fp16 __attribute__((ext_vector_type(4)));

__device__ __forceinline__ unsigned short f2h(float x) {
  _Float16 h = (_Float16)x;
  return __builtin_bit_cast(unsigned short, h);
}

__device__ __forceinline__ void gld_lds16(const unsigned short* g, unsigned short* l) {
  __builtin_amdgcn_global_load_lds(
      (const __attribute__((address_space(1))) unsigned int*)g,
      (__attribute__((address_space(3))) unsigned int*)l, 16, 0, 0);
}

// ---------------- fp32 -> fp16 convert (4 elems/thread) ----------------
__global__ __launch_bounds__(256) void cvt4h(const float* __restrict__ in,
                                             unsigned short* __restrict__ out, int n4) {
  int i = blockIdx.x * 256 + threadIdx.x;
  if (i >= n4) return;
  float4 v = ((const float4*)in)[i];
  unsigned long long r = (unsigned long long)f2h(v.x)
                       | ((unsigned long long)f2h(v.y) << 16)
                       | ((unsigned long long)f2h(v.z) << 32)
                       | ((unsigned long long)f2h(v.w) << 48);
  ((unsigned long long*)out)[i] = r;
}

// three weight converts in one dispatch
__global__ __launch_bounds__(256) void cvt3w(const float* __restrict__ w0, const float* __restrict__ w1,
                                             const float* __restrict__ w2,
                                             unsigned short* __restrict__ o0, unsigned short* __restrict__ o1,
                                             unsigned short* __restrict__ o2) {
  const int z = blockIdx.y;
  const float* in = (z == 0) ? w0 : (z == 1) ? w1 : w2;
  unsigned short* out = (z == 0) ? o0 : (z == 1) ? o1 : o2;
  int i = blockIdx.x * 256 + threadIdx.x;
  float4 v = ((const float4*)in)[i];
  unsigned long long r = (unsigned long long)f2h(v.x)
                       | ((unsigned long long)f2h(v.y) << 16)
                       | ((unsigned long long)f2h(v.z) << 32)
                       | ((unsigned long long)f2h(v.w) << 48);
  ((unsigned long long*)out)[i] = r;
}

// ---------------- fused QKV projection GEMM, BK=64, XCD-swizzled ----------------
// 1-D grid 1536: xcd = bid&7 owns M-tile band [xcd*8, xcd*8+7] for all (tN, z).
// Within XCD: m_local fastest -> 8 consecutive blocks share one W-tile; the 2MB
// X band stays resident in that XCD's L2 across all 24 (tN,z) passes.
__global__ __launch_bounds__(256) void gemm_qkv(
    const unsigned short* __restrict__ Xh,
    const unsigned short* __restrict__ Wqh, const unsigned short* __restrict__ Wkh,
    const unsigned short* __restrict__ Wvh,
    const float* __restrict__ bq, const float* __restrict__ bk, const float* __restrict__ bv,
    unsigned short* __restrict__ Qh, unsigned short* __restrict__ Kh,
    unsigned short* __restrict__ Vt) {
  __shared__ unsigned short lA[128 * 64]; // 16 KB
  __shared__ unsigned short lB[128 * 64]; // 16 KB
  const int L = blockIdx.x;
  const int xcd = L & 7, rr = L >> 3;
  const int mloc = rr & 7, widx = rr >> 3;   // widx 0..23
  const int tNi = widx & 7, z = widx >> 3;   // z 0..2
  const int tM = (xcd * 8 + mloc) * 128, tN = tNi * 128;

  const unsigned short* W = (z == 0) ? Wqh : (z == 1) ? Wkh : Wvh;
  const float* bias = (z == 0) ? bq : (z == 1) ? bk : bv;

  const int tid = threadIdx.x;
  const int wave = tid >> 6, lane = tid & 63;
  const int quad = lane >> 4, l16 = lane & 15;
  const int wr = (wave >> 1) * 64, wc = (wave & 1) * 64;

  f32x4 acc[4][4] = {};

  // staging: thread handles chunks i*256+tid (i=0..3); row = i*32 + tid>>3
  const int rB = tid >> 3;
  const int colOff = (((tid & 7) ^ (rB & 7))) * 8;
  const unsigned short* gA[4];
  const unsigned short* gB[4];
#pragma unroll
  for (int i = 0; i < 4; ++i) {
    gA[i] = Xh + (size_t)(tM + i * 32 + rB) * SD + colOff;
    gB[i] = W  + (size_t)(tN + i * 32 + rB) * SD + colOff;
  }
  unsigned short* dA[4];
  unsigned short* dB[4];
#pragma unroll
  for (int i = 0; i < 4; ++i) {
    dA[i] = lA + (i * 256 + wave * 64) * 8;
    dB[i] = lB + (i * 256 + wave * 64) * 8;
  }
  const int swl = l16 & 7;

  for (int k0 = 0; k0 < SD; k0 += 64) {
    __syncthreads();
#pragma unroll
    for (int i = 0; i < 4; ++i) gld_lds16(gA[i] + k0, dA[i]);
#pragma unroll
    for (int i = 0; i < 4; ++i) gld_lds16(gB[i] + k0, dB[i]);
    __syncthreads();

#pragma unroll
    for (int ks = 0; ks < 2; ++ks) {
      h8 af[4], bf[4];
#pragma unroll
      for (int mi = 0; mi < 4; ++mi)
        af[mi] = *(const h8*)(lA + (wr + mi * 16 + l16) * 64 + (((ks * 4 + quad) ^ swl) * 8));
#pragma unroll
      for (int ni = 0; ni < 4; ++ni)
        bf[ni] = *(const h8*)(lB + (wc + ni * 16 + l16) * 64 + (((ks * 4 + quad) ^ swl) * 8));
#pragma unroll
      for (int mi = 0; mi < 4; ++mi)
#pragma unroll
        for (int ni = 0; ni < 4; ++ni)
          acc[mi][ni] = __builtin_amdgcn_mfma_f32_16x16x32_f16(af[mi], bf[ni], acc[mi][ni], 0, 0, 0);
    }
  }

  // epilogue: C/D layout col=lane&15, row=quad*4+reg
  if (z == 2) {
#pragma unroll
    for (int ni = 0; ni < 4; ++ni) {
      const int gn = tN + wc + ni * 16 + l16;
      const float bb = bias[gn];
#pragma unroll
      for (int mi = 0; mi < 4; ++mi) {
        const int gm = tM + wr + mi * 16 + quad * 4;
        const int vb = gm >> 11, vs = gm & 2047;
        unsigned long long wv = 0;
#pragma unroll
        for (int r = 0; r < 4; ++r)
          wv |= (unsigned long long)f2h(acc[mi][ni][r] + bb) << (16 * r);
        *(unsigned long long*)(Vt + (size_t)(vb * 1024 + gn) * SS + vs) = wv;
      }
    }
  } else {
    const float sc = (z == 0) ? 0.18033688011112042f : 1.0f; // 1/8*log2(e)
    unsigned short* C = (z == 0) ? Qh : Kh;
#pragma unroll
    for (int ni = 0; ni < 4; ++ni) {
      const int gn = tN + wc + ni * 16 + l16;
      const float bb = bias[gn];
#pragma unroll
      for (int mi = 0; mi < 4; ++mi)
#pragma unroll
        for (int r = 0; r < 4; ++r) {
          const int gm = tM + wr + mi * 16 + quad * 4 + r;
          C[(size_t)gm * SD + gn] = f2h((acc[mi][ni][r] + bb) * sc);
        }
    }
  }
}

// ---------------- attention: 128 q/block, 32 q/wave, broadcast V b128 ----------------
// S^T = K·Q^T (A=K-frag K=32, B=Q-frag) -> C: col=l16=query, row=quad*4+r=key
// p = exp2(s) in-register = B-operand layout of mfma_f32_16x16x16f16 -> no P LDS.
// V-frag: lane reads FULL 16B chunk (2g+qh)^swl (quad&1 pair broadcasts), selects
// its h4 in-register -> conflict-free 4-clk ds_read_b128.
__global__ __launch_bounds__(256, 4) void attn(const unsigned short* __restrict__ Qh,
                                               const unsigned short* __restrict__ Kh,
                                               const unsigned short* __restrict__ Vt,
                                               float* __restrict__ out) {
  __shared__ unsigned short lK[2][64 * 64]; // 8 KB each
  __shared__ unsigned short lV[2][64 * 64]; // 8 KB each
  const int tid = threadIdx.x;
  const int wave = tid >> 6, lane = tid & 63;
  const int quad = lane >> 4, l16 = lane & 15;
  const int qh = quad >> 1, ql = quad & 1;
  // XCD swizzle: all 16 q-tiles of one bh share an XCD (bid%8 == bh%8)
  const int bid = blockIdx.x;                      // grid 1024
  const int bh = (bid & 7) | (((bid >> 3) & 7) << 3);
  const int qt = bid >> 6;                         // 0..15
  const int b = bh >> 4, h = bh & 15;
  const int qsA = qt * 128 + wave * 16;            // this wave's first 16 queries
  // half B = qsA + 64

  // Q fragments (1/8*log2e pre-folded in GEMM epilogue)
  const unsigned short* qpA = Qh + ((size_t)(b * SS + qsA + l16)) * SD + h * 64 + quad * 8;
  const unsigned short* qpB = qpA + (size_t)64 * SD;
  h8 aqA0 = *(const h8*)(qpA);
  h8 aqA1 = *(const h8*)(qpA + 32);
  h8 aqB0 = *(const h8*)(qpB);
  h8 aqB1 = *(const h8*)(qpB + 32);

  // staging: thread handles tile chunks tid and 256+tid, XOR-swizzled source
  const int row0 = tid >> 3, cs0 = (tid & 7) ^ (row0 & 7);
  const int row1 = row0 + 32, cs1 = (tid & 7) ^ (row1 & 7);
  const unsigned short* kS0 = Kh + ((size_t)(b * SS + row0)) * SD + h * 64 + cs0 * 8;
  const unsigned short* kS1 = Kh + ((size_t)(b * SS + row1)) * SD + h * 64 + cs1 * 8;
  const unsigned short* vS0 = Vt + ((size_t)(bh * 64 + row0)) * SS + cs0 * 8;
  const unsigned short* vS1 = Vt + ((size_t)(bh * 64 + row1)) * SS + cs1 * 8;
  unsigned short* dK0 = &lK[0][wave * 512];
  unsigned short* dK1 = &lK[0][2048 + wave * 512];
  unsigned short* dV0 = &lV[0][wave * 512];
  unsigned short* dV1 = &lV[0][2048 + wave * 512];

  f32x4 ovA[4] = {}, ovB[4] = {};
  float l_accA = 0.f, l_accB = 0.f;
  const int swl = l16 & 7;

  // prologue: stage tile 0 into buf 0
  gld_lds16(kS0, dK0); gld_lds16(kS1, dK1);
  gld_lds16(vS0, dV0); gld_lds16(vS1, dV1);
  kS0 += 64 * SD; kS1 += 64 * SD; vS0 += 64; vS1 += 64;

  for (int kt = 0; kt < 32; ++kt) {
    const int buf = kt & 1;
    __syncthreads(); // tile kt resident; prev compute on other buf done
    if (kt < 31) {
      const int o = (buf ^ 1) * 64 * 64;
      gld_lds16(kS0, dK0 + o); gld_lds16(kS1, dK1 + o);
      gld_lds16(vS0, dV0 + o); gld_lds16(vS1, dV1 + o);
      kS0 += 64 * SD; kS1 += 64 * SD; vS0 += 64; vS1 += 64;
    }
    const unsigned short* Kt = lK[buf];
    const unsigned short* Vl = lV[buf];

    // QK^T: 16 MFMA K=32 (K-frags shared by both query halves)
    f32x4 sA[4], sB[4];
#pragma unroll
    for (int nt = 0; nt < 4; ++nt) {
      const unsigned short* kr = Kt + (nt * 16 + l16) * 64;
      h8 kf0 = *(const h8*)(kr + ((quad ^ swl) * 8));
      h8 kf1 = *(const h8*)(kr + (((4 + quad) ^ swl) * 8));
      f32x4 zA = {};
      zA = __builtin_amdgcn_mfma_f32_16x16x32_f16(kf0, aqA0, zA, 0, 0, 0);
      sA[nt] = __builtin_amdgcn_mfma_f32_16x16x32_f16(kf1, aqA1, zA, 0, 0, 0);
      f32x4 zB = {};
      zB = __builtin_amdgcn_mfma_f32_16x16x32_f16(kf0, aqB0, zB, 0, 0, 0);
      sB[nt] = __builtin_amdgcn_mfma_f32_16x16x32_f16(kf1, aqB1, zB, 0, 0, 0);
    }

    // per 16-key group g: V-frags (broadcast b128) + exp2 + PV for both halves
#pragma unroll
    for (int g = 0; g < 4; ++g) {
      h4 vf[4];
#pragma unroll
      for (int f = 0; f < 4; ++f) {
        h8 vv = *(const h8*)(Vl + (f * 16 + l16) * 64 + (((g * 2 + qh) ^ swl) * 8));
        h4 lo = __builtin_shufflevector(vv, vv, 0, 1, 2, 3);
        h4 hi = __builtin_shufflevector(vv, vv, 4, 5, 6, 7);
        vf[f] = ql ? hi : lo;
      }
      {
        float p0 = __builtin_amdgcn_exp2f(sA[g][0]);
        float p1 = __builtin_amdgcn_exp2f(sA[g][1]);
        float p2 = __builtin_amdgcn_exp2f(sA[g][2]);
        float p3 = __builtin_amdgcn_exp2f(sA[g][3]);
        l_accA += (p0 + p1) + (p2 + p3);
        fp16x2 lo = __builtin_amdgcn_cvt_pkrtz(p0, p1);
        fp16x2 hi = __builtin_amdgcn_cvt_pkrtz(p2, p3);
        h4 pp = __builtin_bit_cast(h4, __builtin_shufflevector(lo, hi, 0, 1, 2, 3));
#pragma unroll
        for (int f = 0; f < 4; ++f)
          ovA[f] = __builtin_amdgcn_mfma_f32_16x16x16f16(vf[f], pp, ovA[f], 0, 0, 0);
      }
      {
        float p0 = __builtin_amdgcn_exp2f(sB[g][0]);
        float p1 = __builtin_amdgcn_exp2f(sB[g][1]);
        float p2 = __builtin_amdgcn_exp2f(sB[g][2]);
        float p3 = __builtin_amdgcn_exp2f(sB[g][3]);
        l_accB += (p0 + p1) + (p2 + p3);
        fp16x2 lo = __builtin_amdgcn_cvt_pkrtz(p0, p1);
        fp16x2 hi = __builtin_amdgcn_cvt_pkrtz(p2, p3);
        h4 pp = __builtin_bit_cast(h4, __builtin_shufflevector(lo, hi, 0, 1, 2, 3));
#pragma unroll
        for (int f = 0; f < 4; ++f)
          ovB[f] = __builtin_amdgcn_mfma_f32_16x16x16f16(vf[f], pp, ovB[f], 0, 0, 0);
      }
    }
  }
  // l: reduce across quads (same query = l16)
  float ltA = l_accA;
  ltA += __shfl_xor(ltA, 16);
  ltA += __shfl_xor(ltA, 32);
  const float invA = 1.0f / ltA;
  float ltB = l_accB;
  ltB += __shfl_xor(ltB, 16);
  ltB += __shfl_xor(ltB, 32);
  const float invB = 1.0f / ltB;
  // O^T: lane holds query=l16, d = f*16 + quad*4 + r -> float4 stores
  float* orowA = out + ((size_t)(b * SS + qsA + l16)) * SD + h * 64 + quad * 4;
  float* orowB = orowA + (size_t)64 * SD;
#pragma unroll
  for (int f = 0; f < 4; ++f) {
    float4 w;
    w.x = ovA[f][0] * invA; w.y = ovA[f][1] * invA;
    w.z = ovA[f][2] * invA; w.w = ovA[f][3] * invA;
    *(float4*)(orowA + f * 16) = w;
    float4 u;
    u.x = ovB[f][0] * invB; u.y = ovB[f][1] * invB;
    u.z = ovB[f][2] * invB; u.w = ovB[f][3] * invB;
    *(float4*)(orowB + f * 16) = u;
  }
}

extern "C" void kernel_launch(void* const* d_in, const int* in_sizes, int n_in,
                              void* d_out, int out_size, void* d_ws, size_t ws_size,
                              hipStream_t stream) {
  const float* hs = (const float*)d_in[0];
  const float* Wq = (const float*)d_in[1];
  const float* bq = (const float*)d_in[2];
  const float* Wk = (const float*)d_in[3];
  const float* bk = (const float*)d_in[4];
  const float* Wv = (const float*)d_in[5];
  const float* bv = (const float*)d_in[6];
  float* out = (float*)d_out;

  char* ws = (char*)d_ws;
  // layout: Xh 16M | Wq/Wk/Wv 2M each | Qh/Kh/Vt 16M each ~ 70MB
  unsigned short* Xh  = (unsigned short*)(ws);
  unsigned short* Wqh = (unsigned short*)(ws + 16777216);
  unsigned short* Wkh = (unsigned short*)(ws + 16777216 + 2097152);
  unsigned short* Wvh = (unsigned short*)(ws + 16777216 + 2 * 2097152);
  unsigned short* Qh  = (unsigned short*)(ws + 16777216 + 3 * 2097152);
  unsigned short* Kh  = Qh + (size_t)SM * SD;
  unsigned short* Vt  = Kh + (size_t)SM * SD;

  cvt4h<<<dim3(8192), dim3(256), 0, stream>>>(hs, Xh, SM * SD / 4);
  cvt3w<<<dim3(1024, 3), dim3(256), 0, stream>>>(Wq, Wk, Wv, Wqh, Wkh, Wvh);
  gemm_qkv<<<dim3(1536), dim3(256), 0, stream>>>(
      Xh, Wqh, Wkh, Wvh, bq, bk, bv, Qh, Kh, Vt);
  attn<<<dim3(SB * SH * (SS / 128)), dim3(256), 0, stream>>>(Qh, Kh, Vt, out);
}

// Round 7
// 251.135 us; speedup vs baseline: 2.7451x; 1.0254x over previous
//
#include <hip/hip_runtime.h>
#include <math.h>

// Problem constants
#define SB 4
#define SS 2048
#define SD 1024
#define SH 16
#define SHD 64
#define SM (SB * SS) // 8192 rows

using f32x4 = __attribute__((ext_vector_type(4))) float;
using h8    = __attribute__((ext_vector_type(8))) _Float16;
using h4    = __attribute__((ext_vector_type(4))) _Float16;
using fp16x2 = __fp16 __attribute__((ext_vector_type(2)));
using fp16x4 = __fp16 __attribute__((ext_vector_type(4)));

__device__ __forceinline__ unsigned short f2h(float x) {
  _Float16 h = (_Float16)x;
  return __builtin_bit_cast(unsigned short, h);
}

__device__ __forceinline__ void gld_lds16(const unsigned short* g, unsigned short* l) {
  __builtin_amdgcn_global_load_lds(
      (const __attribute__((address_space(1))) unsigned int*)g,
      (__attribute__((address_space(3))) unsigned int*)l, 16, 0, 0);
}

// ---------------- fp32 -> fp16 convert (4 elems/thread) ----------------
__global__ __launch_bounds__(256) void cvt4h(const float* __restrict__ in,
                                             unsigned short* __restrict__ out, int n4) {
  int i = blockIdx.x * 256 + threadIdx.x;
  if (i >= n4) return;
  float4 v = ((const float4*)in)[i];
  unsigned long long r = (unsigned long long)f2h(v.x)
                       | ((unsigned long long)f2h(v.y) << 16)
                       | ((unsigned long long)f2h(v.z) << 32)
                       | ((unsigned long long)f2h(v.w) << 48);
  ((unsigned long long*)out)[i] = r;
}

// three weight converts in one dispatch
__global__ __launch_bounds__(256) void cvt3w(const float* __restrict__ w0, const float* __restrict__ w1,
                                             const float* __restrict__ w2,
                                             unsigned short* __restrict__ o0, unsigned short* __restrict__ o1,
                                             unsigned short* __restrict__ o2) {
  const int z = blockIdx.y;
  const float* in = (z == 0) ? w0 : (z == 1) ? w1 : w2;
  unsigned short* out = (z == 0) ? o0 : (z == 1) ? o1 : o2;
  int i = blockIdx.x * 256 + threadIdx.x;
  float4 v = ((const float4*)in)[i];
  unsigned long long r = (unsigned long long)f2h(v.x)
                       | ((unsigned long long)f2h(v.y) << 16)
                       | ((unsigned long long)f2h(v.z) << 32)
                       | ((unsigned long long)f2h(v.w) << 48);
  ((unsigned long long*)out)[i] = r;
}

// ---------------- fused QKV projection GEMM, BK=64, XCD-swizzled ----------------
// z==0: Qh = (X@Wq^T + bq) * (1/8*log2e)  fp16, [s][1024]   (swapped-operand path)
// z==1: Kh =  X@Wk^T + bk                 fp16, [s][1024]   (swapped-operand path)
// z==2: Vt =  X@Wv^T + bv                 fp16, transposed [bh*64+d][s]
__global__ __launch_bounds__(256) void gemm_qkv(
    const unsigned short* __restrict__ Xh,
    const unsigned short* __restrict__ Wqh, const unsigned short* __restrict__ Wkh,
    const unsigned short* __restrict__ Wvh,
    const float* __restrict__ bq, const float* __restrict__ bk, const float* __restrict__ bv,
    unsigned short* __restrict__ Qh, unsigned short* __restrict__ Kh,
    unsigned short* __restrict__ Vt) {
  __shared__ unsigned short lA[128 * 64]; // 16 KB
  __shared__ unsigned short lB[128 * 64]; // 16 KB
  const int L = blockIdx.x;
  const int xcd = L & 7, rr = L >> 3;
  const int mloc = rr & 7, widx = rr >> 3;   // widx 0..23
  const int tNi = widx & 7, z = widx >> 3;   // z 0..2
  const int tM = (xcd * 8 + mloc) * 128, tN = tNi * 128;

  const unsigned short* W = (z == 0) ? Wqh : (z == 1) ? Wkh : Wvh;
  const float* bias = (z == 0) ? bq : (z == 1) ? bk : bv;

  const int tid = threadIdx.x;
  const int wave = tid >> 6, lane = tid & 63;
  const int quad = lane >> 4, l16 = lane & 15;
  const int wr = (wave >> 1) * 64, wc = (wave & 1) * 64;

  f32x4 acc[4][4] = {};

  const int rB = tid >> 3;
  const int colOff = (((tid & 7) ^ (rB & 7))) * 8;
  const unsigned short* gA[4];
  const unsigned short* gB[4];
#pragma unroll
  for (int i = 0; i < 4; ++i) {
    gA[i] = Xh + (size_t)(tM + i * 32 + rB) * SD + colOff;
    gB[i] = W  + (size_t)(tN + i * 32 + rB) * SD + colOff;
  }
  unsigned short* dA[4];
  unsigned short* dB[4];
#pragma unroll
  for (int i = 0; i < 4; ++i) {
    dA[i] = lA + (i * 256 + wave * 64) * 8;
    dB[i] = lB + (i * 256 + wave * 64) * 8;
  }
  const int swl = l16 & 7;

  if (z == 2) {
    for (int k0 = 0; k0 < SD; k0 += 64) {
      __syncthreads();
#pragma unroll
      for (int i = 0; i < 4; ++i) gld_lds16(gA[i] + k0, dA[i]);
#pragma unroll
      for (int i = 0; i < 4; ++i) gld_lds16(gB[i] + k0, dB[i]);
      __syncthreads();
#pragma unroll
      for (int ks = 0; ks < 2; ++ks) {
        h8 af[4], bf[4];
#pragma unroll
        for (int mi = 0; mi < 4; ++mi)
          af[mi] = *(const h8*)(lA + (wr + mi * 16 + l16) * 64 + (((ks * 4 + quad) ^ swl) * 8));
#pragma unroll
        for (int ni = 0; ni < 4; ++ni)
          bf[ni] = *(const h8*)(lB + (wc + ni * 16 + l16) * 64 + (((ks * 4 + quad) ^ swl) * 8));
#pragma unroll
        for (int mi = 0; mi < 4; ++mi)
#pragma unroll
          for (int ni = 0; ni < 4; ++ni)
            acc[mi][ni] = __builtin_amdgcn_mfma_f32_16x16x32_f16(af[mi], bf[ni], acc[mi][ni], 0, 0, 0);
      }
    }
    // C/D: col=l16 -> gn, row=quad*4+r -> gm (s-direction) ; pack r -> b64
#pragma unroll
    for (int ni = 0; ni < 4; ++ni) {
      const int gn = tN + wc + ni * 16 + l16;
      const float bb = bias[gn];
#pragma unroll
      for (int mi = 0; mi < 4; ++mi) {
        const int gm = tM + wr + mi * 16 + quad * 4;
        const int vb = gm >> 11, vs = gm & 2047;
        unsigned long long wv = 0;
#pragma unroll
        for (int r = 0; r < 4; ++r)
          wv |= (unsigned long long)f2h(acc[mi][ni][r] + bb) << (16 * r);
        *(unsigned long long*)(Vt + (size_t)(vb * 1024 + gn) * SS + vs) = wv;
      }
    }
  } else {
    // swapped operands: D m-dim = W rows (gn), n-dim = X rows (gm)
    for (int k0 = 0; k0 < SD; k0 += 64) {
      __syncthreads();
#pragma unroll
      for (int i = 0; i < 4; ++i) gld_lds16(gA[i] + k0, dA[i]);
#pragma unroll
      for (int i = 0; i < 4; ++i) gld_lds16(gB[i] + k0, dB[i]);
      __syncthreads();
#pragma unroll
      for (int ks = 0; ks < 2; ++ks) {
        h8 af[4], bf[4];
#pragma unroll
        for (int mi = 0; mi < 4; ++mi)
          af[mi] = *(const h8*)(lA + (wr + mi * 16 + l16) * 64 + (((ks * 4 + quad) ^ swl) * 8));
#pragma unroll
        for (int ni = 0; ni < 4; ++ni)
          bf[ni] = *(const h8*)(lB + (wc + ni * 16 + l16) * 64 + (((ks * 4 + quad) ^ swl) * 8));
#pragma unroll
        for (int mi = 0; mi < 4; ++mi)
#pragma unroll
          for (int ni = 0; ni < 4; ++ni)
            acc[mi][ni] = __builtin_amdgcn_mfma_f32_16x16x32_f16(bf[ni], af[mi], acc[mi][ni], 0, 0, 0);
      }
    }
    // C/D: col=l16 -> gm (X row), row=quad*4+r -> gn (consecutive!) -> b64 store
    const float sc = (z == 0) ? 0.18033688011112042f : 1.0f; // 1/8*log2(e)
    unsigned short* C = (z == 0) ? Qh : Kh;
#pragma unroll
    for (int mi = 0; mi < 4; ++mi) {
      const int gm = tM + wr + mi * 16 + l16;
#pragma unroll
      for (int ni = 0; ni < 4; ++ni) {
        const int gnb = tN + wc + ni * 16 + quad * 4;
        const float4 bb4 = *(const float4*)(bias + gnb);
        unsigned long long wv;
        wv  = (unsigned long long)f2h((acc[mi][ni][0] + bb4.x) * sc);
        wv |= (unsigned long long)f2h((acc[mi][ni][1] + bb4.y) * sc) << 16;
        wv |= (unsigned long long)f2h((acc[mi][ni][2] + bb4.z) * sc) << 32;
        wv |= (unsigned long long)f2h((acc[mi][ni][3] + bb4.w) * sc) << 48;
        *(unsigned long long*)(C + (size_t)gm * SD + gnb) = wv;
      }
    }
  }
}

// ---------------- attention: 128 q/block, 32 q/wave, K=32 PV via swizzled P LDS ----
// S^T = K·Q^T (A=K-frag K=32, B=Q-frag) -> C: col=l16=query, row=g*16+quad*4+r=key
// P tile per wave [query=16][key=64], 16B chunk c stored at c^(l16&7):
//   write b64 (4 keys), read b128 -> B-operand of K=32 PV MFMA.
// V-frag: full b128 chunk = A-operand (8 consecutive keys), shared by both halves.
__global__ __launch_bounds__(256, 4) void attn(const unsigned short* __restrict__ Qh,
                                               const unsigned short* __restrict__ Kh,
                                               const unsigned short* __restrict__ Vt,
                                               float* __restrict__ out) {
  __shared__ unsigned short lK[2][64 * 64]; // 16 KB
  __shared__ unsigned short lV[2][64 * 64]; // 16 KB
  __shared__ unsigned short pl[4 * 16 * 64]; // 8 KB, per-wave P tile
  const int tid = threadIdx.x;
  const int wave = tid >> 6, lane = tid & 63;
  const int quad = lane >> 4, l16 = lane & 15;
  const int qh = quad >> 1, ql = quad & 1;
  // XCD swizzle: all 16 q-tiles of one bh share an XCD (bid%8 == bh%8)
  const int bid = blockIdx.x;                      // grid 1024
  const int bh = (bid & 7) | (((bid >> 3) & 7) << 3);
  const int qt = bid >> 6;                         // 0..15
  const int b = bh >> 4, h = bh & 15;
  const int qsA = qt * 128 + wave * 16;            // half B = qsA + 64

  const unsigned short* qpA = Qh + ((size_t)(b * SS + qsA + l16)) * SD + h * 64 + quad * 8;
  const unsigned short* qpB = qpA + (size_t)64 * SD;
  h8 aqA0 = *(const h8*)(qpA);
  h8 aqA1 = *(const h8*)(qpA + 32);
  h8 aqB0 = *(const h8*)(qpB);
  h8 aqB1 = *(const h8*)(qpB + 32);

  const int row0 = tid >> 3, cs0 = (tid & 7) ^ (row0 & 7);
  const int row1 = row0 + 32, cs1 = (tid & 7) ^ (row1 & 7);
  const unsigned short* kS0 = Kh + ((size_t)(b * SS + row0)) * SD + h * 64 + cs0 * 8;
  const unsigned short* kS1 = Kh + ((size_t)(b * SS + row1)) * SD + h * 64 + cs1 * 8;
  const unsigned short* vS0 = Vt + ((size_t)(bh * 64 + row0)) * SS + cs0 * 8;
  const unsigned short* vS1 = Vt + ((size_t)(bh * 64 + row1)) * SS + cs1 * 8;
  unsigned short* dK0 = &lK[0][wave * 512];
  unsigned short* dK1 = &lK[0][2048 + wave * 512];
  unsigned short* dV0 = &lV[0][wave * 512];
  unsigned short* dV1 = &lV[0][2048 + wave * 512];

  f32x4 ovA[4] = {}, ovB[4] = {};
  float l_accA = 0.f, l_accB = 0.f;
  const int swl = l16 & 7;
  unsigned short* plw = pl + wave * 1024;          // 16 rows x 64 shorts
  unsigned short* pwr = plw + l16 * 64;            // this lane's query row
  unsigned short* pwrW = pwr + ql * 4;             // write base (sub-chunk)

  gld_lds16(kS0, dK0); gld_lds16(kS1, dK1);
  gld_lds16(vS0, dV0); gld_lds16(vS1, dV1);
  kS0 += 64 * SD; kS1 += 64 * SD; vS0 += 64; vS1 += 64;

  for (int kt = 0; kt < 32; ++kt) {
    const int buf = kt & 1;
    __syncthreads();
    if (kt < 31) {
      const int o = (buf ^ 1) * 64 * 64;
      gld_lds16(kS0, dK0 + o); gld_lds16(kS1, dK1 + o);
      gld_lds16(vS0, dV0 + o); gld_lds16(vS1, dV1 + o);
      kS0 += 64 * SD; kS1 += 64 * SD; vS0 += 64; vS1 += 64;
    }
    const unsigned short* Kt = lK[buf];
    const unsigned short* Vl = lV[buf];

    // QK^T: 16 MFMA K=32 (K-frags shared by both query halves)
    f32x4 sA[4], sB[4];
#pragma unroll
    for (int nt = 0; nt < 4; ++nt) {
      const unsigned short* kr = Kt + (nt * 16 + l16) * 64;
      h8 kf0 = *(const h8*)(kr + ((quad ^ swl) * 8));
      h8 kf1 = *(const h8*)(kr + (((4 + quad) ^ swl) * 8));
      f32x4 zA = {};
      zA = __builtin_amdgcn_mfma_f32_16x16x32_f16(kf0, aqA0, zA, 0, 0, 0);
      sA[nt] = __builtin_amdgcn_mfma_f32_16x16x32_f16(kf1, aqA1, zA, 0, 0, 0);
      f32x4 zB = {};
      zB = __builtin_amdgcn_mfma_f32_16x16x32_f16(kf0, aqB0, zB, 0, 0, 0);
      sB[nt] = __builtin_amdgcn_mfma_f32_16x16x32_f16(kf1, aqB1, zB, 0, 0, 0);
    }

    // half A: exp/pack -> P writes (key chunk (2g+qh)^swl, sub ql*4)
#pragma unroll
    for (int g = 0; g < 4; ++g) {
      float p0 = __builtin_amdgcn_exp2f(sA[g][0]);
      float p1 = __builtin_amdgcn_exp2f(sA[g][1]);
      float p2 = __builtin_amdgcn_exp2f(sA[g][2]);
      float p3 = __builtin_amdgcn_exp2f(sA[g][3]);
      l_accA += (p0 + p1) + (p2 + p3);
      fp16x2 lo = __builtin_amdgcn_cvt_pkrtz(p0, p1);
      fp16x2 hi = __builtin_amdgcn_cvt_pkrtz(p2, p3);
      fp16x4 pk = __builtin_shufflevector(lo, hi, 0, 1, 2, 3);
      *(unsigned long long*)(pwrW + ((2 * g + qh) ^ swl) * 8) =
          __builtin_bit_cast(unsigned long long, pk);
    }
    asm volatile("s_waitcnt lgkmcnt(0)" ::: "memory");
    h8 pbA0 = *(const h8*)(pwr + ((quad ^ swl) * 8));
    h8 pbA1 = *(const h8*)(pwr + (((4 + quad) ^ swl) * 8));

    // half B writes (DS in-order per wave: execute after pbA reads -> WAR safe)
#pragma unroll
    for (int g = 0; g < 4; ++g) {
      float p0 = __builtin_amdgcn_exp2f(sB[g][0]);
      float p1 = __builtin_amdgcn_exp2f(sB[g][1]);
      float p2 = __builtin_amdgcn_exp2f(sB[g][2]);
      float p3 = __builtin_amdgcn_exp2f(sB[g][3]);
      l_accB += (p0 + p1) + (p2 + p3);
      fp16x2 lo = __builtin_amdgcn_cvt_pkrtz(p0, p1);
      fp16x2 hi = __builtin_amdgcn_cvt_pkrtz(p2, p3);
      fp16x4 pk = __builtin_shufflevector(lo, hi, 0, 1, 2, 3);
      *(unsigned long long*)(pwrW + ((2 * g + qh) ^ swl) * 8) =
          __builtin_bit_cast(unsigned long long, pk);
    }
    asm volatile("s_waitcnt lgkmcnt(0)" ::: "memory");
    h8 pbB0 = *(const h8*)(pwr + ((quad ^ swl) * 8));
    h8 pbB1 = *(const h8*)(pwr + (((4 + quad) ^ swl) * 8));

    // PV: V-frag b128 loaded once, 4 MFMAs per f (A0,A1,B0,B1)
#pragma unroll
    for (int f = 0; f < 4; ++f) {
      const unsigned short* vr = Vl + (f * 16 + l16) * 64;
      h8 v0 = *(const h8*)(vr + ((quad ^ swl) * 8));
      h8 v1 = *(const h8*)(vr + (((4 + quad) ^ swl) * 8));
      ovA[f] = __builtin_amdgcn_mfma_f32_16x16x32_f16(v0, pbA0, ovA[f], 0, 0, 0);
      ovA[f] = __builtin_amdgcn_mfma_f32_16x16x32_f16(v1, pbA1, ovA[f], 0, 0, 0);
      ovB[f] = __builtin_amdgcn_mfma_f32_16x16x32_f16(v0, pbB0, ovB[f], 0, 0, 0);
      ovB[f] = __builtin_amdgcn_mfma_f32_16x16x32_f16(v1, pbB1, ovB[f], 0, 0, 0);
    }
  }
  // l: reduce across quads (same query = l16)
  float ltA = l_accA;
  ltA += __shfl_xor(ltA, 16);
  ltA += __shfl_xor(ltA, 32);
  const float invA = 1.0f / ltA;
  float ltB = l_accB;
  ltB += __shfl_xor(ltB, 16);
  ltB += __shfl_xor(ltB, 32);
  const float invB = 1.0f / ltB;
  float* orowA = out + ((size_t)(b * SS + qsA + l16)) * SD + h * 64 + quad * 4;
  float* orowB = orowA + (size_t)64 * SD;
#pragma unroll
  for (int f = 0; f < 4; ++f) {
    float4 w;
    w.x = ovA[f][0] * invA; w.y = ovA[f][1] * invA;
    w.z = ovA[f][2] * invA; w.w = ovA[f][3] * invA;
    *(float4*)(orowA + f * 16) = w;
    float4 u;
    u.x = ovB[f][0] * invB; u.y = ovB[f][1] * invB;
    u.z = ovB[f][2] * invB; u.w = ovB[f][3] * invB;
    *(float4*)(orowB + f * 16) = u;
  }
}

extern "C" void kernel_launch(void* const* d_in, const int* in_sizes, int n_in,
                              void* d_out, int out_size, void* d_ws, size_t ws_size,
                              hipStream_t stream) {
  const float* hs = (const float*)d_in[0];
  const float* Wq = (const float*)d_in[1];
  const float* bq = (const float*)d_in[2];
  const float* Wk = (const float*)d_in[3];
  const float* bk = (const float*)d_in[4];
  const float* Wv = (const float*)d_in[5];
  const float* bv = (const float*)d_in[6];
  float* out = (float*)d_out;

  char* ws = (char*)d_ws;
  unsigned short* Xh  = (unsigned short*)(ws);
  unsigned short* Wqh = (unsigned short*)(ws + 16777216);
  unsigned short* Wkh = (unsigned short*)(ws + 16777216 + 2097152);
  unsigned short* Wvh = (unsigned short*)(ws + 16777216 + 2 * 2097152);
  unsigned short* Qh  = (unsigned short*)(ws + 16777216 + 3 * 2097152);
  unsigned short* Kh  = Qh + (size_t)SM * SD;
  unsigned short* Vt  = Kh + (size_t)SM * SD;

  cvt4h<<<dim3(8192), dim3(256), 0, stream>>>(hs, Xh, SM * SD / 4);
  cvt3w<<<dim3(1024, 3), dim3(256), 0, stream>>>(Wq, Wk, Wv, Wqh, Wkh, Wvh);
  gemm_qkv<<<dim3(1536), dim3(256), 0, stream>>>(
      Xh, Wqh, Wkh, Wvh, bq, bk, bv, Qh, Kh, Vt);
  attn<<<dim3(SB * SH * (SS / 128)), dim3(256), 0, stream>>>(Qh, Kh, Vt, out);
}